// Round 21
// baseline (73.440 us; speedup 1.0000x reference)
//
#include <hip/hip_runtime.h>
#include <math.h>

#define MM 16
#define CC 345
#define MC (MM*CC)   // 5520
#define KTOP 4
// Guard threshold in tc-space (validated R15/R20: absmax unchanged, ~0.5% trigger).
#define GAP_THR 3e-7f
#define NT 512

__device__ __forceinline__ float fexp(float x) { return __expf(x); }
__device__ __forceinline__ float flog(float x) { return __logf(x); }

// width-16 reductions over a 16-lane group
__device__ __forceinline__ float rmax16(float v) {
    #pragma unroll
    for (int off = 8; off; off >>= 1) v = fmaxf(v, __shfl_xor(v, off, 16));
    return v;
}
__device__ __forceinline__ float rmin16(float v) {
    #pragma unroll
    for (int off = 8; off; off >>= 1) v = fminf(v, __shfl_xor(v, off, 16));
    return v;
}
__device__ __forceinline__ float rsum16(float v) {
    #pragma unroll
    for (int off = 8; off; off >>= 1) v += __shfl_xor(v, off, 16);
    return v;
}
// width-32 reductions over a 32-lane group
__device__ __forceinline__ float rmax32(float v) {
    #pragma unroll
    for (int off = 16; off; off >>= 1) v = fmaxf(v, __shfl_xor(v, off, 32));
    return v;
}
__device__ __forceinline__ float rsum32(float v) {
    #pragma unroll
    for (int off = 16; off; off >>= 1) v += __shfl_xor(v, off, 32);
    return v;
}

// One block per batch row b. 512 threads = 8 waves. 3 barriers.
__global__ __launch_bounds__(NT)
void ens_main(const float* __restrict__ y, const int* __restrict__ labels,
              float* __restrict__ out, float* __restrict__ partial, int B)
{
    const int b   = blockIdx.x;
    const int tid = threadIdx.x;

    __shared__ float sl[MC + 64];     // logits tile (+pad), written by phase 2
    __shared__ float sems[CC];        // ems_out (only sems[label] consumed)
    __shared__ float s_truep[MM], s_epl[MM], s_mx[MM];
    __shared__ float s_w[MM], s_pw[MM];
    __shared__ float s_red[NT/64];

    const int label = labels[b];
    const float* yb = y + (size_t)b * MC;

    // ---- Phase 2 (fused staging): 32 lanes per m read GLOBAL directly
    // (coalesced 128B segments), mirror to LDS for phase 4, compute stats.
    // mx is exp-free and order-independent -> bit-identical to round-1 max.
    {
        const int m = tid >> 5;
        const int l = tid & 31;
        const float* row = yb + m * CC;
        float* srow = sl + m * CC;
        float v[11];
        float mx = -INFINITY;
        #pragma unroll
        for (int k = 0; k < 11; ++k) {
            const int c = l + (k << 5);
            if (c < CC) { v[k] = row[c]; srow[c] = v[k]; mx = fmaxf(mx, v[k]); }
            else          v[k] = 0.f;
        }
        mx = rmax32(mx);
        float se = 0.f;
        #pragma unroll
        for (int k = 0; k < 11; ++k) {
            const int c = l + (k << 5);
            if (c < CC) se += fexp(v[k] - mx);
        }
        se = rsum32(se);
        if (l == 0) {
            const float lt = row[label];
            s_mx[m]    = mx;                          // exact max, reused by 3b
            s_truep[m] = fexp(lt - mx) / se;          // fast probs[b,m,label]
            s_epl[m]   = -(lt - mx - flog(se));       // -log_softmax[b,m,label]
        }
    }
    __syncthreads();   // #1 — sl + stats ready

    // ---- Phase 3 entirely on wave 0 (R10-verbatim 64-lane form: 4 redundant
    // 16-lane groups, in-wave bit-exact guard, no internal barriers).
    if (tid < 64) {
        const int l  = tid;
        const int lm = l & 15;
        const int mq = l >> 4;
        const int g  = l & 15;

        const float tpv  = s_truep[lm];
        const float eplv = s_epl[lm];

        // 3a: fast per-b math + top-4 by rank
        const float mxs = rmax16(tpv);
        const float e0  = fexp(tpv - mxs);
        const float tc  = e0 / rsum16(e0);                 // true_confs (fast)
        const float s1  = fmaxf(rsum16(fabsf(tc)), 1e-12f);
        const float wm  = tc / s1;                         // weighted_mat
        int rank = 0;
        #pragma unroll
        for (int j = 0; j < MM; ++j) {
            const float vj = __shfl(tc, j, 16);
            rank += (vj > tc) || (vj == tc && j < lm);
        }
        bool sel = (rank < KTOP);
        const float val4 = rmin16(sel ? tc : INFINITY);    // smallest selected
        const float val5 = rmax16(sel ? -INFINITY : tc);   // largest unselected
        const bool need = (val4 - val5 < GAP_THR);         // wave-uniform, rare

        // 3b (R10-verbatim): BIT-EXACT round-1 chain — libm expf, strided-16
        // ascending global reads + xor-tree rsum16 (same exact mx), serial
        // ascending denominator, tie-ranked top-4.
        if (need) {
            float tpp4[4];
            #pragma unroll
            for (int i = 0; i < 4; ++i) {
                const int m = i * 4 + mq;
                const float* row = yb + m * CC;
                const float mx = s_mx[m];                  // bitwise phase-2 mx
                float se = 0.f;
                for (int c = g; c < CC; c += 16) se += expf(row[c] - mx);
                se = rsum16(se);
                tpp4[i] = expf(row[label] - mx) / se;
            }
            float tppv = 0.f;
            {
                const int src = (lm & 3) << 4;
                #pragma unroll
                for (int i = 0; i < 4; ++i) {
                    const float a_ = __shfl(tpp4[i], src, 64);
                    if ((lm >> 2) == i) tppv = a_;
                }
            }
            const float mxx = rmax16(tppv);
            const float ev  = expf(tppv - mxx);
            float ses = 0.f;
            #pragma unroll
            for (int m = 0; m < MM; ++m) ses += __shfl(ev, m, 16); // ascending
            const float tcpv = ev / ses;
            int rk = 0;
            #pragma unroll
            for (int j = 0; j < MM; ++j) {
                const float vj = __shfl(tcpv, j, 16);
                rk += (vj > tcpv) || (vj == tcpv && j < lm);
            }
            sel = (rk < KTOP);
        }

        // 3c (R10-verbatim): finish per-b math, publish weights
        const float post = sel ? tc : 0.f;
        const float psum = fmaxf(rsum16(fabsf(post)), 1e-12f);
        const float pw   = post / psum;
        const float mw = rmax16(wm);
        const float ex = fexp(wm - mw);
        const float xv = ex / rsum16(ex);
        const float mt = rmax16(tc);
        const float et = fexp(tc - mt);
        const float tv = et / rsum16(et);
        const float childp = eplv * xv;
        const float confp  = fmaxf(xv, 0.f) - xv * tv + flog(1.f + fexp(-fabsf(xv)));
        const float childs = rsum16(childp);
        const float confs  = rsum16(confp);
        if (l == 0) {
            partial[(size_t)b * 3 + 0] = childs;
            partial[(size_t)b * 3 + 1] = confs;
        }
        if (l < MM) {
            const size_t off_wm = (size_t)B * CC + 3;
            const size_t off_tc = off_wm + (size_t)B * MM;
            out[off_wm + (size_t)b * MM + l] = xv;  // wm_soft
            out[off_tc + (size_t)b * MM + l] = tc;  // true_confs
            s_w[l]  = wm;
            s_pw[l] = pw;
        }
    }
    __syncthreads();   // #2 — weights ready

    // ---- Phase 4+5 fused (R20-verbatim): ems_out / ems_out_post, then
    // ensemble loss via UNSHIFTED log-sum-exp (|ems| <~ 6, overflow-safe).
    {
        const int c = tid;
        const bool act = (c < CC);
        float a = 0.f;
        if (act) {
            float aa = 0.f, ap = 0.f;
            #pragma unroll
            for (int m = 0; m < MM; ++m) {
                const float vv = sl[m * CC + c];
                aa = fmaf(vv, s_w[m],  aa);
                ap = fmaf(vv, s_pw[m], ap);
            }
            sems[c] = aa;                      // only sems[label] consumed
            out[(size_t)b * CC + c] = ap;      // ems_out_post
            a = aa;
        }
        float e = act ? fexp(a) : 0.f;
        #pragma unroll
        for (int off = 32; off; off >>= 1) e += __shfl_xor(e, off);
        if ((tid & 63) == 0) s_red[tid >> 6] = e;
        __syncthreads();   // #3 — covers sems writes + s_red
        if (tid == 0) {
            float s = 0.f;
            #pragma unroll
            for (int w = 0; w < NT/64; ++w) s += s_red[w];
            partial[(size_t)b * 3 + 2] = -(sems[label] - flog(s));
        }
    }
}

// Two-stage deterministic reduction of per-b partials -> the 3 scalar losses.
__global__ __launch_bounds__(64)
void ens_reduce1(const float* __restrict__ partial, double* __restrict__ ws2, int B)
{
    const int t  = threadIdx.x;     // 0..63
    const int i  = blockIdx.x;      // 0..63
    const int r0 = i * 128 + t * 2; // 128 rows per block
    double c = 0.0, f = 0.0, e = 0.0;
    #pragma unroll
    for (int k = 0; k < 2; ++k) {
        const int r = r0 + k;
        c += (double)partial[(size_t)r * 3 + 0];
        f += (double)partial[(size_t)r * 3 + 1];
        e += (double)partial[(size_t)r * 3 + 2];
    }
    #pragma unroll
    for (int off = 32; off; off >>= 1) {
        c += __shfl_xor(c, off);
        f += __shfl_xor(f, off);
        e += __shfl_xor(e, off);
    }
    if (t == 0) {
        ws2[(size_t)i * 3 + 0] = c;
        ws2[(size_t)i * 3 + 1] = f;
        ws2[(size_t)i * 3 + 2] = e;
    }
}

__global__ __launch_bounds__(64)
void ens_reduce2(const double* __restrict__ ws2, float* __restrict__ out, int B)
{
    const int t = threadIdx.x;
    double c = ws2[(size_t)t * 3 + 0];
    double f = ws2[(size_t)t * 3 + 1];
    double e = ws2[(size_t)t * 3 + 2];
    #pragma unroll
    for (int off = 32; off; off >>= 1) {
        c += __shfl_xor(c, off);
        f += __shfl_xor(f, off);
        e += __shfl_xor(e, off);
    }
    if (t == 0) {
        const size_t base = (size_t)B * CC;
        out[base + 0] = (float)(c / (double)((size_t)B * MM));  // child_loss
        out[base + 1] = (float)(f / (double)((size_t)B * MM));  // confidence_loss
        out[base + 2] = (float)(e / (double)B);                 // ensemble_loss
    }
}

extern "C" void kernel_launch(void* const* d_in, const int* in_sizes, int n_in,
                              void* d_out, int out_size, void* d_ws, size_t ws_size,
                              hipStream_t stream)
{
    const float* y      = (const float*)d_in[0];
    const int*   labels = (const int*)d_in[1];
    const int    B      = in_sizes[1];      // 8192
    float* out     = (float*)d_out;
    float* partial = (float*)d_ws;          // B*3 floats
    double* ws2    = (double*)((char*)d_ws + (((size_t)B * 3 * sizeof(float) + 255) & ~(size_t)255));

    ens_main<<<dim3(B), dim3(NT), 0, stream>>>(y, labels, out, partial, B);
    ens_reduce1<<<dim3(64), dim3(64), 0, stream>>>(partial, ws2, B);
    ens_reduce2<<<dim3(1), dim3(64), 0, stream>>>(ws2, out, B);
}